// Round 10
// baseline (257.670 us; speedup 1.0000x reference)
//
#include <hip/hip_runtime.h>

// (B,T,E,H,HS) = (8,1024,1024,16,64). Inputs/output: float32 (proven r6-r12).
// Internals bf16 MFMA. r14 = BK=64 XOR-swizzled GEMM (conflicts 6.29M -> 0).
// r15 FAILED: direct-global K/V thrashed L2. r17/r18 hung -- shelved. r19 =
// hoisted pointers (qkv 81.5us). r20 REGRESSED (runtime dbuf idx -> addr
// remat). r21 = 2-phase GEMM: NULL (m99/m100) -> GEMMs stay r19-form.
// r22 = attn_v9 swapped-QK^T in-register P (time-neutral, freed 18KB LDS,
// kept: enables this). r23 = attn_v10: K/V staged via global_load_lds into
// DOUBLE-BUFFERED linear LDS with both-sides XOR swizzle (rule #21, GEMM-
// proven), ONE barrier per chunk (vmcnt drain after compute), literal buffer
// indices (unroll-by-2). Removes per-chunk: 1 barrier + vmcnt-wait + 4
// ds_write_b128 reg-staging chain; frees 16 VGPR.
#define B_  8
#define T_  1024
#define E_  1024
#define H_  16
#define HS_ 64
#define K_  1024

typedef __bf16 bf16x8 __attribute__((ext_vector_type(8)));
typedef __bf16 bf16x4 __attribute__((ext_vector_type(4)));
typedef float  f32x4  __attribute__((ext_vector_type(4)));
typedef unsigned short us;

__device__ __forceinline__ us f2bf(float f) {           // RNE
    union { float f; unsigned int i; } c; c.f = f;
    unsigned int x = c.i;
    return (us)((x + 0x7fff + ((x >> 16) & 1)) >> 16);
}
__device__ __forceinline__ us f2bf_t(float f) {         // truncate (P only)
    union { float f; unsigned int i; } c; c.f = f;
    return (us)(c.i >> 16);
}
__device__ __forceinline__ bf16x8 cvt8(const float* p) {
    float4 a = *reinterpret_cast<const float4*>(p);
    float4 b = *reinterpret_cast<const float4*>(p + 4);
    union { bf16x8 v; us u[8]; } c;
    c.u[0] = f2bf(a.x); c.u[1] = f2bf(a.y); c.u[2] = f2bf(a.z); c.u[3] = f2bf(a.w);
    c.u[4] = f2bf(b.x); c.u[5] = f2bf(b.y); c.u[6] = f2bf(b.z); c.u[7] = f2bf(b.w);
    return c.v;
}
// Async global->LDS 16B/lane; LDS dest = wave-uniform base + lane*16 (m97/m104).
__device__ __forceinline__ void async_cp16(const us* g, us* l) {
    __builtin_amdgcn_global_load_lds((const unsigned int*)g, (unsigned int*)l, 16, 0, 0);
}

// K=16 bf16 MFMA (instruction exists on gfx950 per ISA 10; builtin name hedged)
__device__ __forceinline__ f32x4 mfma_pv16(bf16x4 a, bf16x4 b, f32x4 c) {
#if __has_builtin(__builtin_amdgcn_mfma_f32_16x16x16_bf16)
    return __builtin_amdgcn_mfma_f32_16x16x16_bf16(a, b, c, 0, 0, 0);
#elif __has_builtin(__builtin_amdgcn_mfma_f32_16x16x16bf16_1k)
    typedef short s16x4 __attribute__((ext_vector_type(4)));
    union U { bf16x4 b; s16x4 s; };
    U ua, ub; ua.b = a; ub.b = b;
    return __builtin_amdgcn_mfma_f32_16x16x16bf16_1k(ua.s, ub.s, c, 0, 0, 0);
#else
    f32x4 d = c;
    asm("v_mfma_f32_16x16x16_bf16 %0, %1, %2, %0" : "+v"(d) : "v"(a), "v"(b));
    return d;
#endif
}

// ---------------------------------------------------------------------------
// One-shot f32 -> bf16 conversion of x and the four weight matrices.
// ---------------------------------------------------------------------------
__global__ __launch_bounds__(256) void cvt_kernel(
    const float* __restrict__ sx, const float* __restrict__ sq,
    const float* __restrict__ sk, const float* __restrict__ sv,
    const float* __restrict__ sp,
    us* __restrict__ dx, us* __restrict__ dq, us* __restrict__ dk,
    us* __restrict__ dv, us* __restrict__ dp)
{
    const int y = blockIdx.y;
    const float* src = (y == 0) ? sx : (y == 1) ? sq : (y == 2) ? sk : (y == 3) ? sv : sp;
    us*          dst = (y == 0) ? dx : (y == 1) ? dq : (y == 2) ? dk : (y == 3) ? dv : dp;
    const size_t n = (y == 0) ? (size_t)B_ * T_ * E_ : (size_t)E_ * E_;
    const size_t i = ((size_t)blockIdx.x * 256 + threadIdx.x) * 8;
    if (i >= n) return;
    *reinterpret_cast<bf16x8*>(dst + i) = cvt8(src + i);
}

// ---------------------------------------------------------------------------
// 128x128 all-bf16 GEMM, BK=64, global_load_lds width-16 staging, XOR-swizzled
// LDS (conflict-free, r14), hoisted pointers (r19). 1-phase: 2-phase proven
// NULL here (r21 == r19; m99/m100). Do NOT grow the tile (r10) or force
// min-waves bounds (r11).
// ---------------------------------------------------------------------------
__global__ __launch_bounds__(256) void qkv_gf(
    const us* __restrict__ A,
    const us* __restrict__ Wq, const us* __restrict__ Wk, const us* __restrict__ Wv,
    us* __restrict__ q, us* __restrict__ k, us* __restrict__ vT)
{
    const int type = blockIdx.z;
    const us* Bm = (type == 0) ? Wq : (type == 1) ? Wk : Wv;
    us* out      = (type == 0) ? q  : (type == 1) ? k  : vT;
    const int vtrans = (type == 2);

    __shared__ __align__(16) us As[128 * 64];
    __shared__ __align__(16) us Bs[128 * 64];

    const int tid  = threadIdx.x;
    const int lane = tid & 63;
    const int w    = tid >> 6;
    const int quad = lane >> 4;
    const int l15  = lane & 15;
    const int wm   = w >> 1, wn = w & 1;
    const int row0 = blockIdx.x * 128;
    const int col0 = blockIdx.y * 128;
    const int x7   = l15 & 7;          // fragment row & 7 (rows are +multiple of 8)
    const int ca0  = (quad ^ x7) * 8;          // swizzled read chunk, kk=0
    const int ca1  = ((4 + quad) ^ x7) * 8;    // kk=1

    // hoisted staging pointers: advance 64 elems (128B) per K-step
    const us* pa[4]; const us* pb[4];
#pragma unroll
    for (int i = 0; i < 4; ++i) {
        const int idx = tid + i * 256;          // 0..1023
        const int r   = idx >> 3;               // tile row 0..127
        const int c8  = ((idx & 7) ^ (r & 7)) * 8;  // inverse-swizzled src chunk
        pa[i] = A  + (size_t)(row0 + r) * K_ + c8;
        pb[i] = Bm + (size_t)(col0 + r) * K_ + c8;
    }

    f32x4 acc[4][4] = {};
    for (int k0 = 0; k0 < K_; k0 += 64) {
        __syncthreads();
#pragma unroll
        for (int i = 0; i < 4; ++i) {
            async_cp16(pa[i], &As[(tid + i * 256) * 8]);
            async_cp16(pb[i], &Bs[(tid + i * 256) * 8]);
            pa[i] += 64; pb[i] += 64;
        }
        __syncthreads();
#pragma unroll
        for (int kk = 0; kk < 2; ++kk) {
            const int ca = kk ? ca1 : ca0;
            bf16x8 af[4], bf[4];
#pragma unroll
            for (int t = 0; t < 4; ++t) {
                af[t] = *reinterpret_cast<const bf16x8*>(&As[(wm * 64 + t * 16 + l15) * 64 + ca]);
                bf[t] = *reinterpret_cast<const bf16x8*>(&Bs[(wn * 64 + t * 16 + l15) * 64 + ca]);
            }
#pragma unroll
            for (int mt = 0; mt < 4; ++mt)
#pragma unroll
                for (int nt = 0; nt < 4; ++nt)
                    acc[mt][nt] = __builtin_amdgcn_mfma_f32_16x16x32_bf16(af[mt], bf[nt], acc[mt][nt], 0, 0, 0);
        }
    }

#pragma unroll
    for (int mt = 0; mt < 4; ++mt)
#pragma unroll
        for (int nt = 0; nt < 4; ++nt)
#pragma unroll
            for (int r = 0; r < 4; ++r) {
                const int m = row0 + wm * 64 + mt * 16 + quad * 4 + r;
                const int n = col0 + wn * 64 + nt * 16 + l15;
                const int b = m >> 10, t = m & 1023;
                const int h = n >> 6,  d = n & 63;
                const us vb = f2bf(acc[mt][nt][r]);
                if (vtrans)  out[((size_t)((b * 16 + h) * 64 + d)) * 1024 + t] = vb;
                else         out[((size_t)(b * 16 + h) * 1024 + t) * 64 + d] = vb;
            }
}

__global__ __launch_bounds__(256) void proj_gf(
    const us* __restrict__ A, const us* __restrict__ Bm, float* __restrict__ C)
{
    __shared__ __align__(16) us As[128 * 64];
    __shared__ __align__(16) us Bs[128 * 64];

    const int tid  = threadIdx.x;
    const int lane = tid & 63;
    const int w    = tid >> 6;
    const int quad = lane >> 4;
    const int l15  = lane & 15;
    const int wm   = w >> 1, wn = w & 1;
    const int row0 = blockIdx.x * 128;
    const int col0 = blockIdx.y * 128;
    const int x7   = l15 & 7;
    const int ca0  = (quad ^ x7) * 8;
    const int ca1  = ((4 + quad) ^ x7) * 8;

    const us* pa[4]; const us* pb[4];
#pragma unroll
    for (int i = 0; i < 4; ++i) {
        const int idx = tid + i * 256;
        const int r   = idx >> 3;
        const int c8  = ((idx & 7) ^ (r & 7)) * 8;
        pa[i] = A  + (size_t)(row0 + r) * K_ + c8;
        pb[i] = Bm + (size_t)(col0 + r) * K_ + c8;
    }

    f32x4 acc[4][4] = {};
    for (int k0 = 0; k0 < K_; k0 += 64) {
        __syncthreads();
#pragma unroll
        for (int i = 0; i < 4; ++i) {
            async_cp16(pa[i], &As[(tid + i * 256) * 8]);
            async_cp16(pb[i], &Bs[(tid + i * 256) * 8]);
            pa[i] += 64; pb[i] += 64;
        }
        __syncthreads();
#pragma unroll
        for (int kk = 0; kk < 2; ++kk) {
            const int ca = kk ? ca1 : ca0;
            bf16x8 af[4], bf[4];
#pragma unroll
            for (int t = 0; t < 4; ++t) {
                af[t] = *reinterpret_cast<const bf16x8*>(&As[(wm * 64 + t * 16 + l15) * 64 + ca]);
                bf[t] = *reinterpret_cast<const bf16x8*>(&Bs[(wn * 64 + t * 16 + l15) * 64 + ca]);
            }
#pragma unroll
            for (int mt = 0; mt < 4; ++mt)
#pragma unroll
                for (int nt = 0; nt < 4; ++nt)
                    acc[mt][nt] = __builtin_amdgcn_mfma_f32_16x16x32_bf16(af[mt], bf[nt], acc[mt][nt], 0, 0, 0);
        }
    }

    // f32 output: 16-lane runs are already 64B-contiguous — store direct.
#pragma unroll
    for (int mt = 0; mt < 4; ++mt)
#pragma unroll
        for (int nt = 0; nt < 4; ++nt)
#pragma unroll
            for (int r = 0; r < 4; ++r) {
                const int m = row0 + wm * 64 + mt * 16 + quad * 4 + r;
                const int n = col0 + wn * 64 + nt * 16 + l15;
                C[(size_t)m * E_ + n] = acc[mt][nt][r];
            }
}

// ---------------------------------------------------------------------------
// attn_v10: swapped QK^T + in-register P (r22) + async double-buffered K/V
// staging. Per chunk: issue global_load_lds for NEXT chunk into buf[P^1],
// compute QK/exp/PV from buf[P], ONE __syncthreads (drains loads after
// compute). LDS linear [2][64*64] per tensor, both-sides XOR chunk swizzle:
//   stage: LDS chunk (idx&7) <- global col chunk ((idx&7)^(row&7))
//   read:  want col chunk c -> read LDS chunk (c^(row&7))   (involution)
// K-reads b128: 2-way banks (GEMM-proven). V-reads b64: 8 chunk groups x 2
// lanes -> 2-way banks (free).
// ---------------------------------------------------------------------------
#define CSCALE 0.18033688011112042f   // 0.125 * log2(e)

#define ATT_BODY(P, CH)                                                        \
    {                                                                          \
        const int s0 = (CH) * 64;                                              \
        const bool actA = ((CH) <= tA);                                        \
        if ((CH) + 1 < nch) {      /* prefetch next chunk into other buf */    \
            async_cp16(kp0, &kt[(P) ^ 1][d0]);                                 \
            async_cp16(kp1, &kt[(P) ^ 1][d1]);                                 \
            async_cp16(vp0, &vt[(P) ^ 1][d0]);                                 \
            async_cp16(vp1, &vt[(P) ^ 1][d1]);                                 \
            kp0 += 64 * HS_; kp1 += 64 * HS_; vp0 += 64; vp1 += 64;            \
        }                                                                      \
        f32x4 sA[4] = {}, sB[4] = {};                                          \
        _Pragma("unroll")                                                      \
        for (int nt = 0; nt < 4; ++nt) {                                       \
            const int krow = (nt * 16 + l15) * 64;                             \
            bf16x8 kf0 = *reinterpret_cast<const bf16x8*>(&kt[P][krow + ca0]); \
            bf16x8 kf1 = *reinterpret_cast<const bf16x8*>(&kt[P][krow + ca1]); \
            sB[nt] = __builtin_amdgcn_mfma_f32_16x16x32_bf16(kf0, qfB0, sB[nt], 0, 0, 0); \
            sB[nt] = __builtin_amdgcn_mfma_f32_16x16x32_bf16(kf1, qfB1, sB[nt], 0, 0, 0); \
            if (actA) {                                                        \
                sA[nt] = __builtin_amdgcn_mfma_f32_16x16x32_bf16(kf0, qfA0, sA[nt], 0, 0, 0); \
                sA[nt] = __builtin_amdgcn_mfma_f32_16x16x32_bf16(kf1, qfA1, sA[nt], 0, 0, 0); \
            }                                                                  \
        }                                                                      \
        if ((CH) == tB) {                                                      \
            _Pragma("unroll")                                                  \
            for (int nt = 0; nt < 4; ++nt)                                     \
                _Pragma("unroll")                                              \
                for (int r = 0; r < 4; ++r)                                    \
                    if (s0 + nt * 16 + quad * 4 + r > rowB + l15) sB[nt][r] = -1e30f; \
        }                                                                      \
        if ((CH) == tA) {                                                      \
            _Pragma("unroll")                                                  \
            for (int nt = 0; nt < 4; ++nt)                                     \
                _Pragma("unroll")                                              \
                for (int r = 0; r < 4; ++r)                                    \
                    if (s0 + nt * 16 + quad * 4 + r > rowA + l15) sA[nt][r] = -1e30f; \
        }                                                                      \
        bf16x4 paB[4], paA[4];                                                 \
        _Pragma("unroll")                                                      \
        for (int nt = 0; nt < 4; ++nt) {                                       \
            union { bf16x4 v; us u[4]; } pk;                                   \
            _Pragma("unroll")                                                  \
            for (int r = 0; r < 4; ++r) {                                      \
                const float p = exp2f(sB[nt][r] * CSCALE);                     \
                lB += p;                                                       \
                pk.u[r] = f2bf_t(p);                                           \
            }                                                                  \
            paB[nt] = pk.v;                                                    \
        }                                                                      \
        if (actA) {                                                            \
            _Pragma("unroll")                                                  \
            for (int nt = 0; nt < 4; ++nt) {                                   \
                union { bf16x4 v; us u[4]; } pk;                               \
                _Pragma("unroll")                                              \
                for (int r = 0; r < 4; ++r) {                                  \
                    const float p = exp2f(sA[nt][r] * CSCALE);                 \
                    lA += p;                                                   \
                    pk.u[r] = f2bf_t(p);                                       \
                }                                                              \
                paA[nt] = pk.v;                                                \
            }                                                                  \
        }                                                                      \
        _Pragma("unroll")                                                      \
        for (int dt = 0; dt < 4; ++dt) {                                       \
            const int vrow = (dt * 16 + l15) * 64;                             \
            _Pragma("unroll")                                                  \
            for (int nt = 0; nt < 4; ++nt) {                                   \
                const int vc = ((2 * nt + (quad >> 1)) ^ x7) * 8 + (quad & 1) * 4; \
                const bf16x4 vf = *reinterpret_cast<const bf16x4*>(&vt[P][vrow + vc]); \
                oB[dt] = mfma_pv16(paB[nt], vf, oB[dt]);                       \
                if (actA) oA[dt] = mfma_pv16(paA[nt], vf, oA[dt]);             \
            }                                                                  \
        }                                                                      \
        __syncthreads();                                                       \
    }

__global__ __launch_bounds__(256) void attn_v10(
    const us* __restrict__ Q, const us* __restrict__ K,
    const us* __restrict__ VT, us* __restrict__ O)
{
    const int px = blockIdx.x;          // 0..7
    const int bh = blockIdx.y;
    const int tA = px, tB = 15 - px;    // uniform work: (p+1)+(16-p)=17 units
    const size_t base  = (size_t)bh * T_ * HS_;
    const size_t baseT = (size_t)bh * HS_ * T_;
    const int tid  = threadIdx.x;
    const int lane = tid & 63;
    const int w    = tid >> 6;
    const int quad = lane >> 4;
    const int l15  = lane & 15;
    const int x7   = l15 & 7;
    const int ca0  = (quad ^ x7) * 8;          // K-read swizzled chunks
    const int ca1  = ((4 + quad) ^ x7) * 8;

    __shared__ __align__(16) us kt[2][64 * 64];
    __shared__ __align__(16) us vt[2][64 * 64];

    const int rowA = tA * 64 + w * 16;
    const int rowB = tB * 64 + w * 16;

    bf16x8 qfA0, qfA1, qfB0, qfB1;
    {
        const us* qa = Q + base + (size_t)(rowA + l15) * HS_ + quad * 8;
        const us* qb = Q + base + (size_t)(rowB + l15) * HS_ + quad * 8;
        qfA0 = *reinterpret_cast<const bf16x8*>(qa);
        qfA1 = *reinterpret_cast<const bf16x8*>(qa + 32);
        qfB0 = *reinterpret_cast<const bf16x8*>(qb);
        qfB1 = *reinterpret_cast<const bf16x8*>(qb + 32);
    }

    // staging geometry: idx = tid + i*256 (i<2); row = idx>>3, src chunk
    // inverse-swizzled; LDS dest linear idx*8 elems (wave-uniform + lane*16B).
    const int idx0 = tid, idx1 = tid + 256;
    const int r0 = idx0 >> 3, r1 = idx1 >> 3;
    const int d0 = idx0 * 8,  d1 = idx1 * 8;
    const us* kp0 = K + base + (size_t)r0 * HS_ + ((idx0 & 7) ^ (r0 & 7)) * 8;
    const us* kp1 = K + base + (size_t)r1 * HS_ + ((idx1 & 7) ^ (r1 & 7)) * 8;
    const us* vp0 = VT + baseT + (size_t)r0 * T_ + ((idx0 & 7) ^ (r0 & 7)) * 8;
    const us* vp1 = VT + baseT + (size_t)r1 * T_ + ((idx1 & 7) ^ (r1 & 7)) * 8;

    float lA = 0.f, lB = 0.f;           // per-lane row sum (q-row = l15)
    f32x4 oA[4] = {}, oB[4] = {};

    const int nch = tB + 1;
    // prologue: stage chunk 0 into buffer 0
    async_cp16(kp0, &kt[0][d0]);
    async_cp16(kp1, &kt[0][d1]);
    async_cp16(vp0, &vt[0][d0]);
    async_cp16(vp1, &vt[0][d1]);
    kp0 += 64 * HS_; kp1 += 64 * HS_; vp0 += 64; vp1 += 64;
    __syncthreads();                    // implicit vmcnt(0): chunk 0 ready

    for (int ch = 0; ch < nch; ch += 2) {
        ATT_BODY(0, ch)
        if (ch + 1 < nch) ATT_BODY(1, ch + 1)
    }

    // epilogue: reduce row sums across the 4 quads, gather per-output-row
    lA += __shfl_xor(lA, 16); lA += __shfl_xor(lA, 32);
    lB += __shfl_xor(lB, 16); lB += __shfl_xor(lB, 32);

    const int b = bh >> 4, h = bh & 15;
#pragma unroll
    for (int r = 0; r < 4; ++r) {
        const int src = (lane & 48) + quad * 4 + r;   // lane holding row quad*4+r
        const float invA = 1.f / __shfl(lA, src);
        const float invB = 1.f / __shfl(lB, src);
        const size_t offA = ((size_t)b * T_ + rowA + quad * 4 + r) * E_ + h * HS_;
        const size_t offB = ((size_t)b * T_ + rowB + quad * 4 + r) * E_ + h * HS_;
#pragma unroll
        for (int dt = 0; dt < 4; ++dt) {
            O[offA + dt * 16 + l15] = f2bf(oA[dt][r] * invA);
            O[offB + dt * 16 + l15] = f2bf(oB[dt][r] * invB);
        }
    }
}

// ===========================================================================
extern "C" void kernel_launch(void* const* d_in, const int* in_sizes, int n_in,
                              void* d_out, int out_size, void* d_ws, size_t ws_size,
                              hipStream_t stream) {
    // setup_inputs order: x, Wk, Wq, Wv, Wproj, i  (all float32)
    const float* x  = (const float*)d_in[0];
    const float* Wk = (const float*)d_in[1];
    const float* Wq = (const float*)d_in[2];
    const float* Wv = (const float*)d_in[3];
    const float* Wp = (const float*)d_in[4];

    const size_t qe = (size_t)B_ * H_ * T_ * HS_;   // 8,388,608 elems
    const size_t we = (size_t)E_ * E_;              // 1,048,576 elems

    // ws: xb(16M, reused as o) | wq | wk | wv | wp | q | k | vT  (~76 MB)
    us* xb = (us*)d_ws;
    us* wq = xb + qe;
    us* wk = wq + we;
    us* wv = wk + we;
    us* wp = wv + we;
    us* q  = wp + we;
    us* k  = q + qe;
    us* vT = k + qe;
    us* o  = xb;   // xb dead after qkv_gf

    cvt_kernel<<<dim3(4096, 5), 256, 0, stream>>>(x, Wq, Wk, Wv, Wp,
                                                  xb, wq, wk, wv, wp);
    qkv_gf<<<dim3(64, 8, 3), 256, 0, stream>>>(xb, wq, wk, wv, q, k, vT);
    attn_v10<<<dim3(8, 128), 256, 0, stream>>>(q, k, vT, o);
    proj_gf<<<dim3(64, 8), 256, 0, stream>>>(o, wp, (float*)d_out);
}